// Round 5
// baseline (10508.024 us; speedup 1.0000x reference)
//
#include <hip/hip_runtime.h>
#include <math.h>

#define B_      8
#define N_      16384
#define CIN_    128
#define COUT_   256
#define NS_     4096
#define FPS_T   1024
#define PPT     16      // N_ / FPS_T

// XLA-CPU-contracted distance: fma(dz,dz, fma(dy,dy, dx*dx)) — bit-exact vs gold.
static __device__ __forceinline__ float sqdist_xla(float px, float py, float pz,
                                                   float cx, float cy, float cz) {
  float dx = __fsub_rn(px, cx);
  float dy = __fsub_rn(py, cy);
  float dz = __fsub_rn(pz, cz);
  return __fmaf_rn(dz, dz, __fmaf_rn(dy, dy, __fmul_rn(dx, dx)));
}

// Blocks 0..7: FPS (one block/batch, 1024 thr, 16 pts/thr, all state in VGPRs).
// Blocks 8..71: Gram partials G = F^T F + column sums S, overlapped on idle CUs.
__global__ __launch_bounds__(1024, 1) void k1_fps_gram(
    const float* __restrict__ points, const float* __restrict__ features,
    float* __restrict__ outP, int* __restrict__ idxw,
    float* __restrict__ Gpart, float* __restrict__ Spart)
{
  const int tid = threadIdx.x;
  if (blockIdx.x < B_) {
    // ---------------- FPS ----------------
    const int b = blockIdx.x;
    const float* __restrict__ P = points + (size_t)b * N_ * 3;

    float px[PPT], py[PPT], pz[PPT], dd[PPT];
    #pragma unroll
    for (int k = 0; k < PPT; ++k) {
      const int n = tid * PPT + k;
      px[k] = P[3*n+0]; py[k] = P[3*n+1]; pz[k] = P[3*n+2];
    }

    __shared__ float sv[2][16];
    __shared__ int   si[2][16];
    __shared__ float cent[3];
    const int lane = tid & 63;
    const int wid  = tid >> 6;   // 0..15

    // centroid: sequential f32 accumulation over n (reference emission order), *2^-14 exact
    if (tid < 3) {
      const int c = tid;
      float acc = P[c];
      for (int n = 1; n < N_; ++n) acc = __fadd_rn(acc, P[3*n + c]);
      cent[c] = __fmul_rn(acc, 6.103515625e-05f);
    }
    __syncthreads();
    const float cx0 = cent[0], cy0 = cent[1], cz0 = cent[2];

    int far;
    {
      // d0 pass with fused first-occurrence argmax tracking
      float lm; int lk = 0;
      {
        float d = sqdist_xla(px[0], py[0], pz[0], cx0, cy0, cz0);
        dd[0] = d; lm = d;
      }
      #pragma unroll
      for (int k = 1; k < PPT; ++k) {
        float d = sqdist_xla(px[k], py[k], pz[k], cx0, cy0, cz0);
        dd[k] = d;
        bool keep = (d <= lm);           // ties keep earlier k
        lm = fmaxf(lm, d);
        lk = keep ? lk : k;
      }
      int gi = tid * PPT + lk;
      #pragma unroll
      for (int off = 32; off > 0; off >>= 1) {
        float ov = __shfl_xor(lm, off);
        int   oi = __shfl_xor(gi, off);
        bool better = (ov > lm) || ((ov == lm) && (oi < gi));
        lm = better ? ov : lm;
        gi = better ? oi : gi;
      }
      if (lane == 0) { sv[0][wid] = lm; si[0][wid] = gi; }   // parity 0 (s=-1)
      __syncthreads();
      float bv = sv[0][0]; int bi = si[0][0];
      #pragma unroll
      for (int w = 1; w < 16; ++w) {
        float v = sv[0][w]; int ii = si[0][w];
        bool better = (v > bv) || ((v == bv) && (ii < bi));
        bv = better ? v : bv;
        bi = better ? ii : bi;
      }
      far = bi;
    }
    #pragma unroll
    for (int k = 0; k < PPT; ++k) dd[k] = 1e10f;   // reference init

    for (int s = 0; s < NS_; ++s) {
      // all threads broadcast-load the selected center (uniform addr, L2-hot)
      const float* __restrict__ cp = P + 3 * (size_t)far;
      const float ccx = cp[0], ccy = cp[1], ccz = cp[2];
      if (tid == 0) {
        const size_t ob = ((size_t)b * NS_ + s);
        outP[ob*3+0] = ccx; outP[ob*3+1] = ccy; outP[ob*3+2] = ccz;
        idxw[b*NS_ + s] = far;
      }
      if (s + 1 == NS_) break;            // uniform exit

      float lm = -1.0f; int lk = 0;
      #pragma unroll
      for (int k = 0; k < PPT; ++k) {
        float d  = sqdist_xla(px[k], py[k], pz[k], ccx, ccy, ccz);
        float nd = fminf(dd[k], d);
        dd[k] = nd;
        bool keep = (nd <= lm);
        lm = fmaxf(lm, nd);
        lk = keep ? lk : k;
      }
      int gi = tid * PPT + lk;
      #pragma unroll
      for (int off = 32; off > 0; off >>= 1) {
        float ov = __shfl_xor(lm, off);
        int   oi = __shfl_xor(gi, off);
        bool better = (ov > lm) || ((ov == lm) && (oi < gi));
        lm = better ? ov : lm;
        gi = better ? oi : gi;
      }
      const int pw = (s & 1) ^ 1;         // s=0 -> 1, s=1 -> 0 (d0 used 0)
      if (lane == 0) { sv[pw][wid] = lm; si[pw][wid] = gi; }
      __syncthreads();                    // the ONLY barrier per iteration
      float bv = sv[pw][0]; int bi = si[pw][0];
      #pragma unroll
      for (int w = 1; w < 16; ++w) {
        float v = sv[pw][w]; int ii = si[pw][w];
        bool better = (v > bv) || ((v == bv) && (ii < bi));
        bv = better ? v : bv;
        bi = better ? ii : bi;
      }
      far = bi;
    }
  } else {
    // ---------------- Gram partials (1024 threads) ----------------
    const int gb = (int)blockIdx.x - B_;  // 0..63
    const int b  = gb >> 3;
    const int ch = gb & 7;
    __shared__ float Lf[32][128];
    float acc[4][4];
    #pragma unroll
    for (int i = 0; i < 4; ++i)
      #pragma unroll
      for (int j = 0; j < 4; ++j) acc[i][j] = 0.f;
    float sacc = 0.f;
    const int ti = tid >> 5;   // 0..31 (rows ti*4.. in output)
    const int tj = tid & 31;   // 0..31 (cols tj*4..)
    const float* fb = features + ((size_t)b * N_ + (size_t)ch * 2048) * CIN_;
    for (int t32 = 0; t32 < 64; ++t32) {
      // stage 32 rows x 128 cols: thread (ti,tj) loads row ti, cols tj*4..tj*4+3
      const float4 v0 = *(const float4*)(fb + ((size_t)t32 * 32 + ti) * CIN_ + tj * 4);
      __syncthreads();
      *(float4*)&Lf[ti][tj*4] = v0;
      __syncthreads();
      #pragma unroll 4
      for (int r = 0; r < 32; ++r) {
        const float4 a4 = *(const float4*)&Lf[r][ti*4];
        const float4 b4 = *(const float4*)&Lf[r][tj*4];
        const float av[4] = {a4.x, a4.y, a4.z, a4.w};
        const float bw[4] = {b4.x, b4.y, b4.z, b4.w};
        #pragma unroll
        for (int i = 0; i < 4; ++i)
          #pragma unroll
          for (int j = 0; j < 4; ++j) acc[i][j] = fmaf(av[i], bw[j], acc[i][j]);
      }
      if (tid < 128) {
        #pragma unroll 8
        for (int r = 0; r < 32; ++r) sacc += Lf[r][tid];
      }
    }
    float* gp = Gpart + (size_t)gb * (CIN_*CIN_);
    #pragma unroll
    for (int i = 0; i < 4; ++i)
      #pragma unroll
      for (int j = 0; j < 4; ++j)
        gp[(ti*4+i)*CIN_ + tj*4 + j] = acc[i][j];
    if (tid < 128) Spart[gb*CIN_ + tid] = sacc;
  }
}

__global__ void k2a_reduce(const float* __restrict__ Gpart, const float* __restrict__ Spart,
                           float* __restrict__ Gred, float* __restrict__ Sred)
{
  const int b = blockIdx.x;
  for (int i = threadIdx.x; i < CIN_*CIN_; i += blockDim.x) {
    float s = 0.f;
    #pragma unroll
    for (int c = 0; c < 8; ++c) s += Gpart[((size_t)(b*8+c))*(CIN_*CIN_) + i];
    Gred[(size_t)b*(CIN_*CIN_) + i] = s;
  }
  if (threadIdx.x < CIN_) {
    float s = 0.f;
    #pragma unroll
    for (int c = 0; c < 8; ++c) s += Spart[(b*8+c)*CIN_ + threadIdx.x];
    Sred[b*CIN_ + threadIdx.x] = s;
  }
}

// per (b,o): mu-b = w.S/N ; var = (wGw + 2 b w.S)/N + b^2 - mu^2 ; scale = 1/sqrt(var+eps)
__global__ __launch_bounds__(128) void k2b_stats(
    const float* __restrict__ Gred, const float* __restrict__ Sred,
    const float* __restrict__ W, const float* __restrict__ bias,
    float* __restrict__ stats)
{
  const int b = blockIdx.x >> 8;
  const int o = blockIdx.x & 255;
  const int tid = threadIdx.x;
  __shared__ float sw[CIN_];
  __shared__ float r1[CIN_], r2[CIN_];
  sw[tid] = W[(size_t)o*CIN_ + tid];
  __syncthreads();
  const float* gr = Gred + (size_t)b*CIN_*CIN_ + (size_t)tid*CIN_;
  float g = 0.f;
  #pragma unroll 8
  for (int j = 0; j < CIN_; ++j) g = fmaf(gr[j], sw[j], g);
  r1[tid] = g * sw[tid];
  r2[tid] = sw[tid] * Sred[b*CIN_ + tid];
  __syncthreads();
  for (int stp = 64; stp > 0; stp >>= 1) {
    if (tid < stp) { r1[tid] += r1[tid+stp]; r2[tid] += r2[tid+stp]; }
    __syncthreads();
  }
  if (tid == 0) {
    const float wGw = r1[0], wS = r2[0], bo = bias[o];
    const float invN = 1.0f / (float)N_;
    const float mu  = wS*invN + bo;
    const float ex2 = (wGw + 2.0f*bo*wS)*invN + bo*bo;
    float var = ex2 - mu*mu;
    var = fmaxf(var, 0.0f);
    const float sc = 1.0f / sqrtf(var + 1e-5f);
    stats[((size_t)(b*COUT_ + o))*2 + 0] = wS*invN;  // mu - bias
    stats[((size_t)(b*COUT_ + o))*2 + 1] = sc;
  }
}

// recompute GEMM at sampled rows only, apply norm + relu
__global__ __launch_bounds__(256) void k3_out(
    const float* __restrict__ features, const float* __restrict__ W,
    const int* __restrict__ idxw, const float* __restrict__ stats,
    float* __restrict__ outF)
{
  const int tid = threadIdx.x;
  const int b  = blockIdx.x >> 8;
  const int r  = blockIdx.x & 255;
  const int st = r >> 2, ot = r & 3;
  const int s0 = st * 64, o0 = ot * 64;

  __shared__ float Fs[64][129];
  __shared__ float Wt[64][129];
  __shared__ int   sIdx[64];
  __shared__ float sSub[64], sSc[64];

  if (tid < 64) sIdx[tid] = idxw[b*NS_ + s0 + tid];
  if (tid >= 64 && tid < 128) {
    const int oo = tid - 64;
    sSub[oo] = stats[((size_t)(b*COUT_ + o0 + oo))*2 + 0];
    sSc[oo]  = stats[((size_t)(b*COUT_ + o0 + oo))*2 + 1];
  }
  __syncthreads();
  {
    const int row = tid >> 2;   // 0..63
    const int q   = tid & 3;
    const float* fsrc = features + ((size_t)b*N_ + sIdx[row]) * CIN_;
    const float* wsrc = W + (size_t)(o0 + row) * CIN_;
    #pragma unroll
    for (int v = 0; v < 8; ++v) {
      const int c = q*4 + v*16;
      const float4 fv = *(const float4*)(fsrc + c);
      const float4 wv = *(const float4*)(wsrc + c);
      Fs[row][c+0]=fv.x; Fs[row][c+1]=fv.y; Fs[row][c+2]=fv.z; Fs[row][c+3]=fv.w;
      Wt[row][c+0]=wv.x; Wt[row][c+1]=wv.y; Wt[row][c+2]=wv.z; Wt[row][c+3]=wv.w;
    }
  }
  __syncthreads();

  const int ts = tid >> 4, to = tid & 15;
  float acc[4][4];
  #pragma unroll
  for (int i = 0; i < 4; ++i)
    #pragma unroll
    for (int j = 0; j < 4; ++j) acc[i][j] = 0.f;

  #pragma unroll 4
  for (int k = 0; k < CIN_; ++k) {
    const float a0 = Fs[ts*4+0][k], a1 = Fs[ts*4+1][k], a2 = Fs[ts*4+2][k], a3 = Fs[ts*4+3][k];
    const float w0 = Wt[to*4+0][k], w1 = Wt[to*4+1][k], w2 = Wt[to*4+2][k], w3 = Wt[to*4+3][k];
    acc[0][0]=fmaf(a0,w0,acc[0][0]); acc[0][1]=fmaf(a0,w1,acc[0][1]); acc[0][2]=fmaf(a0,w2,acc[0][2]); acc[0][3]=fmaf(a0,w3,acc[0][3]);
    acc[1][0]=fmaf(a1,w0,acc[1][0]); acc[1][1]=fmaf(a1,w1,acc[1][1]); acc[1][2]=fmaf(a1,w2,acc[1][2]); acc[1][3]=fmaf(a1,w3,acc[1][3]);
    acc[2][0]=fmaf(a2,w0,acc[2][0]); acc[2][1]=fmaf(a2,w1,acc[2][1]); acc[2][2]=fmaf(a2,w2,acc[2][2]); acc[2][3]=fmaf(a2,w3,acc[2][3]);
    acc[3][0]=fmaf(a3,w0,acc[3][0]); acc[3][1]=fmaf(a3,w1,acc[3][1]); acc[3][2]=fmaf(a3,w2,acc[3][2]); acc[3][3]=fmaf(a3,w3,acc[3][3]);
  }

  #pragma unroll
  for (int i = 0; i < 4; ++i) {
    float4 o4;
    o4.x = fmaxf((acc[i][0] - sSub[to*4+0]) * sSc[to*4+0], 0.f);
    o4.y = fmaxf((acc[i][1] - sSub[to*4+1]) * sSc[to*4+1], 0.f);
    o4.z = fmaxf((acc[i][2] - sSub[to*4+2]) * sSc[to*4+2], 0.f);
    o4.w = fmaxf((acc[i][3] - sSub[to*4+3]) * sSc[to*4+3], 0.f);
    *(float4*)&outF[((size_t)b*NS_ + s0 + ts*4 + i)*COUT_ + o0 + to*4] = o4;
  }
}

extern "C" void kernel_launch(void* const* d_in, const int* in_sizes, int n_in,
                              void* d_out, int out_size, void* d_ws, size_t ws_size,
                              hipStream_t stream) {
  (void)in_sizes; (void)n_in; (void)out_size; (void)ws_size;
  const float* points   = (const float*)d_in[0];
  const float* features = (const float*)d_in[1];
  const float* W        = (const float*)d_in[2];
  const float* bias     = (const float*)d_in[3];
  float* out  = (float*)d_out;
  float* outP = out;
  float* outF = out + (size_t)B_*NS_*3;

  char* ws = (char*)d_ws;
  int*   idxw  = (int*)  (ws + 0);                                        // 131072 B
  float* Gpart = (float*)(ws + 131072);                                   // 4 MiB
  float* Spart = (float*)(ws + 131072 + 4194304);                         // 32 KiB
  float* Gred  = (float*)(ws + 131072 + 4194304 + 32768);                 // 512 KiB
  float* Sred  = (float*)(ws + 131072 + 4194304 + 32768 + 524288);        // 4 KiB
  float* stats = (float*)(ws + 131072 + 4194304 + 32768 + 524288 + 4096); // 16 KiB

  k1_fps_gram<<<dim3(B_ + 64), dim3(FPS_T), 0, stream>>>(points, features, outP, idxw, Gpart, Spart);
  k2a_reduce <<<dim3(B_),      dim3(512),   0, stream>>>(Gpart, Spart, Gred, Sred);
  k2b_stats  <<<dim3(B_*COUT_),dim3(CIN_),  0, stream>>>(Gred, Sred, W, bias, stats);
  k3_out     <<<dim3(B_*256),  dim3(256),   0, stream>>>(features, W, idxw, stats, outF);
}

// Round 6
// 7012.300 us; speedup vs baseline: 1.4985x; 1.4985x over previous
//
#include <hip/hip_runtime.h>
#include <math.h>

#define B_      8
#define N_      16384
#define CIN_    128
#define COUT_   256
#define NS_     4096
#define FPS_T   1024
#define PPT     16      // N_ / FPS_T

#define RPT16(X) X(0) X(1) X(2) X(3) X(4) X(5) X(6) X(7) \
                 X(8) X(9) X(10) X(11) X(12) X(13) X(14) X(15)

// XLA-CPU-contracted distance: fma(dz,dz, fma(dy,dy, dx*dx)) — bit-exact vs gold.
static __device__ __forceinline__ float sqdist_xla(float px, float py, float pz,
                                                   float cx, float cy, float cz) {
  float dx = __fsub_rn(px, cx);
  float dy = __fsub_rn(py, cy);
  float dz = __fsub_rn(pz, cz);
  return __fmaf_rn(dz, dz, __fmaf_rn(dy, dy, __fmul_rn(dx, dx)));
}

// Blocks 0..7: FPS (one block/batch, 1024 thr, 16 pts/thr in NAMED SCALAR registers).
// Blocks 8..71: Gram partials G = F^T F + column sums S, overlapped on idle CUs.
__global__ __launch_bounds__(1024, 4) void k1_fps_gram(
    const float* __restrict__ points, const float* __restrict__ features,
    float* __restrict__ outP, int* __restrict__ idxw,
    float* __restrict__ Gpart, float* __restrict__ Spart)
{
  const int tid = threadIdx.x;
  if (blockIdx.x < B_) {
    // ---------------- FPS ----------------
    const int b = blockIdx.x;
    const float* __restrict__ P = points + (size_t)b * N_ * 3;
    const int base = tid * PPT;
    const int lane = tid & 63;
    const int wid  = tid >> 6;   // 0..15

    // 64 named scalars: guaranteed VGPR-resident (no arrays -> no SROA/scratch risk)
    #define DECLP(i) float px##i, py##i, pz##i, dd##i;
    RPT16(DECLP)
    #define LOADP(i) px##i = P[3*(base+(i))+0]; \
                     py##i = P[3*(base+(i))+1]; \
                     pz##i = P[3*(base+(i))+2];
    RPT16(LOADP)

    __shared__ unsigned svv[16];
    __shared__ int      sii[16];
    __shared__ float    cC[3];
    __shared__ float    cent[3];

    // centroid: sequential f32 accumulation over n (reference emission order), *2^-14 exact
    if (tid < 3) {
      const int c = tid;
      float acc = P[c];
      for (int n = 1; n < N_; ++n) acc = __fadd_rn(acc, P[3*n + c]);
      cent[c] = __fmul_rn(acc, 6.103515625e-05f);
    }
    __syncthreads();
    const float cx0 = cent[0], cy0 = cent[1], cz0 = cent[2];

    // selection broadcast: wave-reduce packed key, wave0 block-reduce, lane0 fetch+publish.
    // key = (f32bits(dist) << 32) | ~index  (dist >= 0 -> uint order == float order;
    // ~index makes ties resolve to the SMALLEST index = first occurrence)
    auto select_far = [&](float lmv, int lkv, int s) {
      unsigned long long pk =
          ((unsigned long long)__float_as_uint(lmv) << 32) | (unsigned)(~(base + lkv));
      #pragma unroll
      for (int off = 32; off > 0; off >>= 1) {
        unsigned long long op = __shfl_xor(pk, off);
        pk = (op > pk) ? op : pk;
      }
      if (lane == 0) { svv[wid] = (unsigned)(pk >> 32); sii[wid] = (int)(~(unsigned)pk); }
      __syncthreads();                         // A: candidates visible
      if (wid == 0) {
        unsigned long long p2 = 0ULL;
        if (lane < 16)
          p2 = ((unsigned long long)svv[lane] << 32) | (unsigned)(~sii[lane]);
        #pragma unroll
        for (int off = 8; off > 0; off >>= 1) {
          unsigned long long op = __shfl_xor(p2, off);
          p2 = (op > p2) ? op : p2;
        }
        if (lane == 0) {
          const int bi = (int)(~(unsigned)p2);
          const float* cp = P + 3 * (size_t)bi;
          const float x = cp[0], y = cp[1], z = cp[2];
          cC[0] = x; cC[1] = y; cC[2] = z;
          const size_t ob = (size_t)b * NS_ + s;
          outP[ob*3+0] = x; outP[ob*3+1] = y; outP[ob*3+2] = z;
          idxw[b*NS_ + s] = bi;
        }
      }
      __syncthreads();                         // B: center visible
    };

    // d0 pass: distance to centroid, fused first-occurrence argmax
    {
      float lm = -1.0f; int lk = 0;
      #define SCAN0(i) { float d = sqdist_xla(px##i, py##i, pz##i, cx0, cy0, cz0); \
                         dd##i = d; bool bt = (d > lm); \
                         lk = bt ? (i) : lk; lm = bt ? d : lm; }
      RPT16(SCAN0)
      select_far(lm, lk, 0);
    }
    #define INITD(i) dd##i = 1e10f;
    RPT16(INITD)

    for (int s = 1; s < NS_; ++s) {
      const float ccx = cC[0], ccy = cC[1], ccz = cC[2];
      float lm = -1.0f; int lk = 0;
      #define SCANU(i) { float d = sqdist_xla(px##i, py##i, pz##i, ccx, ccy, ccz); \
                         float nd = fminf(dd##i, d); dd##i = nd; \
                         bool bt = (nd > lm); \
                         lk = bt ? (i) : lk; lm = bt ? nd : lm; }
      RPT16(SCANU)
      select_far(lm, lk, s);
    }
  } else {
    // ---------------- Gram partials (1024 threads) ----------------
    const int gb = (int)blockIdx.x - B_;  // 0..63
    const int b  = gb >> 3;
    const int ch = gb & 7;
    __shared__ float Lf[32][128];
    float acc[4][4];
    #pragma unroll
    for (int i = 0; i < 4; ++i)
      #pragma unroll
      for (int j = 0; j < 4; ++j) acc[i][j] = 0.f;
    float sacc = 0.f;
    const int ti = tid >> 5;   // 0..31
    const int tj = tid & 31;   // 0..31
    const float* fb = features + ((size_t)b * N_ + (size_t)ch * 2048) * CIN_;
    for (int t32 = 0; t32 < 64; ++t32) {
      const float4 v0 = *(const float4*)(fb + ((size_t)t32 * 32 + ti) * CIN_ + tj * 4);
      __syncthreads();
      *(float4*)&Lf[ti][tj*4] = v0;
      __syncthreads();
      #pragma unroll 4
      for (int r = 0; r < 32; ++r) {
        const float4 a4 = *(const float4*)&Lf[r][ti*4];
        const float4 b4 = *(const float4*)&Lf[r][tj*4];
        const float av[4] = {a4.x, a4.y, a4.z, a4.w};
        const float bw[4] = {b4.x, b4.y, b4.z, b4.w};
        #pragma unroll
        for (int i = 0; i < 4; ++i)
          #pragma unroll
          for (int j = 0; j < 4; ++j) acc[i][j] = fmaf(av[i], bw[j], acc[i][j]);
      }
      if (tid < 128) {
        #pragma unroll 8
        for (int r = 0; r < 32; ++r) sacc += Lf[r][tid];
      }
    }
    float* gp = Gpart + (size_t)gb * (CIN_*CIN_);
    #pragma unroll
    for (int i = 0; i < 4; ++i)
      #pragma unroll
      for (int j = 0; j < 4; ++j)
        gp[(ti*4+i)*CIN_ + tj*4 + j] = acc[i][j];
    if (tid < 128) Spart[gb*CIN_ + tid] = sacc;
  }
}

__global__ void k2a_reduce(const float* __restrict__ Gpart, const float* __restrict__ Spart,
                           float* __restrict__ Gred, float* __restrict__ Sred)
{
  const int b = blockIdx.x;
  for (int i = threadIdx.x; i < CIN_*CIN_; i += blockDim.x) {
    float s = 0.f;
    #pragma unroll
    for (int c = 0; c < 8; ++c) s += Gpart[((size_t)(b*8+c))*(CIN_*CIN_) + i];
    Gred[(size_t)b*(CIN_*CIN_) + i] = s;
  }
  if (threadIdx.x < CIN_) {
    float s = 0.f;
    #pragma unroll
    for (int c = 0; c < 8; ++c) s += Spart[(b*8+c)*CIN_ + threadIdx.x];
    Sred[b*CIN_ + threadIdx.x] = s;
  }
}

// per (b,o): mu-b = w.S/N ; var = (wGw + 2 b w.S)/N + b^2 - mu^2 ; scale = 1/sqrt(var+eps)
__global__ __launch_bounds__(128) void k2b_stats(
    const float* __restrict__ Gred, const float* __restrict__ Sred,
    const float* __restrict__ W, const float* __restrict__ bias,
    float* __restrict__ stats)
{
  const int b = blockIdx.x >> 8;
  const int o = blockIdx.x & 255;
  const int tid = threadIdx.x;
  __shared__ float sw[CIN_];
  __shared__ float r1[CIN_], r2[CIN_];
  sw[tid] = W[(size_t)o*CIN_ + tid];
  __syncthreads();
  const float* gr = Gred + (size_t)b*CIN_*CIN_ + (size_t)tid*CIN_;
  float g = 0.f;
  #pragma unroll 8
  for (int j = 0; j < CIN_; ++j) g = fmaf(gr[j], sw[j], g);
  r1[tid] = g * sw[tid];
  r2[tid] = sw[tid] * Sred[b*CIN_ + tid];
  __syncthreads();
  for (int stp = 64; stp > 0; stp >>= 1) {
    if (tid < stp) { r1[tid] += r1[tid+stp]; r2[tid] += r2[tid+stp]; }
    __syncthreads();
  }
  if (tid == 0) {
    const float wGw = r1[0], wS = r2[0], bo = bias[o];
    const float invN = 1.0f / (float)N_;
    const float mu  = wS*invN + bo;
    const float ex2 = (wGw + 2.0f*bo*wS)*invN + bo*bo;
    float var = ex2 - mu*mu;
    var = fmaxf(var, 0.0f);
    const float sc = 1.0f / sqrtf(var + 1e-5f);
    stats[((size_t)(b*COUT_ + o))*2 + 0] = wS*invN;  // mu - bias
    stats[((size_t)(b*COUT_ + o))*2 + 1] = sc;
  }
}

// recompute GEMM at sampled rows only, apply norm + relu
__global__ __launch_bounds__(256) void k3_out(
    const float* __restrict__ features, const float* __restrict__ W,
    const int* __restrict__ idxw, const float* __restrict__ stats,
    float* __restrict__ outF)
{
  const int tid = threadIdx.x;
  const int b  = blockIdx.x >> 8;
  const int r  = blockIdx.x & 255;
  const int st = r >> 2, ot = r & 3;
  const int s0 = st * 64, o0 = ot * 64;

  __shared__ float Fs[64][129];
  __shared__ float Wt[64][129];
  __shared__ int   sIdx[64];
  __shared__ float sSub[64], sSc[64];

  if (tid < 64) sIdx[tid] = idxw[b*NS_ + s0 + tid];
  if (tid >= 64 && tid < 128) {
    const int oo = tid - 64;
    sSub[oo] = stats[((size_t)(b*COUT_ + o0 + oo))*2 + 0];
    sSc[oo]  = stats[((size_t)(b*COUT_ + o0 + oo))*2 + 1];
  }
  __syncthreads();
  {
    const int row = tid >> 2;   // 0..63
    const int q   = tid & 3;
    const float* fsrc = features + ((size_t)b*N_ + sIdx[row]) * CIN_;
    const float* wsrc = W + (size_t)(o0 + row) * CIN_;
    #pragma unroll
    for (int v = 0; v < 8; ++v) {
      const int c = q*4 + v*16;
      const float4 fv = *(const float4*)(fsrc + c);
      const float4 wv = *(const float4*)(wsrc + c);
      Fs[row][c+0]=fv.x; Fs[row][c+1]=fv.y; Fs[row][c+2]=fv.z; Fs[row][c+3]=fv.w;
      Wt[row][c+0]=wv.x; Wt[row][c+1]=wv.y; Wt[row][c+2]=wv.z; Wt[row][c+3]=wv.w;
    }
  }
  __syncthreads();

  const int ts = tid >> 4, to = tid & 15;
  float acc[4][4];
  #pragma unroll
  for (int i = 0; i < 4; ++i)
    #pragma unroll
    for (int j = 0; j < 4; ++j) acc[i][j] = 0.f;

  #pragma unroll 4
  for (int k = 0; k < CIN_; ++k) {
    const float a0 = Fs[ts*4+0][k], a1 = Fs[ts*4+1][k], a2 = Fs[ts*4+2][k], a3 = Fs[ts*4+3][k];
    const float w0 = Wt[to*4+0][k], w1 = Wt[to*4+1][k], w2 = Wt[to*4+2][k], w3 = Wt[to*4+3][k];
    acc[0][0]=fmaf(a0,w0,acc[0][0]); acc[0][1]=fmaf(a0,w1,acc[0][1]); acc[0][2]=fmaf(a0,w2,acc[0][2]); acc[0][3]=fmaf(a0,w3,acc[0][3]);
    acc[1][0]=fmaf(a1,w0,acc[1][0]); acc[1][1]=fmaf(a1,w1,acc[1][1]); acc[1][2]=fmaf(a1,w2,acc[1][2]); acc[1][3]=fmaf(a1,w3,acc[1][3]);
    acc[2][0]=fmaf(a2,w0,acc[2][0]); acc[2][1]=fmaf(a2,w1,acc[2][1]); acc[2][2]=fmaf(a2,w2,acc[2][2]); acc[2][3]=fmaf(a2,w3,acc[2][3]);
    acc[3][0]=fmaf(a3,w0,acc[3][0]); acc[3][1]=fmaf(a3,w1,acc[3][1]); acc[3][2]=fmaf(a3,w2,acc[3][2]); acc[3][3]=fmaf(a3,w3,acc[3][3]);
  }

  #pragma unroll
  for (int i = 0; i < 4; ++i) {
    float4 o4;
    o4.x = fmaxf((acc[i][0] - sSub[to*4+0]) * sSc[to*4+0], 0.f);
    o4.y = fmaxf((acc[i][1] - sSub[to*4+1]) * sSc[to*4+1], 0.f);
    o4.z = fmaxf((acc[i][2] - sSub[to*4+2]) * sSc[to*4+2], 0.f);
    o4.w = fmaxf((acc[i][3] - sSub[to*4+3]) * sSc[to*4+3], 0.f);
    *(float4*)&outF[((size_t)b*NS_ + s0 + ts*4 + i)*COUT_ + o0 + to*4] = o4;
  }
}

extern "C" void kernel_launch(void* const* d_in, const int* in_sizes, int n_in,
                              void* d_out, int out_size, void* d_ws, size_t ws_size,
                              hipStream_t stream) {
  (void)in_sizes; (void)n_in; (void)out_size; (void)ws_size;
  const float* points   = (const float*)d_in[0];
  const float* features = (const float*)d_in[1];
  const float* W        = (const float*)d_in[2];
  const float* bias     = (const float*)d_in[3];
  float* out  = (float*)d_out;
  float* outP = out;
  float* outF = out + (size_t)B_*NS_*3;

  char* ws = (char*)d_ws;
  int*   idxw  = (int*)  (ws + 0);                                        // 131072 B
  float* Gpart = (float*)(ws + 131072);                                   // 4 MiB
  float* Spart = (float*)(ws + 131072 + 4194304);                         // 32 KiB
  float* Gred  = (float*)(ws + 131072 + 4194304 + 32768);                 // 512 KiB
  float* Sred  = (float*)(ws + 131072 + 4194304 + 32768 + 524288);        // 4 KiB
  float* stats = (float*)(ws + 131072 + 4194304 + 32768 + 524288 + 4096); // 16 KiB

  k1_fps_gram<<<dim3(B_ + 64), dim3(FPS_T), 0, stream>>>(points, features, outP, idxw, Gpart, Spart);
  k2a_reduce <<<dim3(B_),      dim3(512),   0, stream>>>(Gpart, Spart, Gred, Sred);
  k2b_stats  <<<dim3(B_*COUT_),dim3(CIN_),  0, stream>>>(Gred, Sred, W, bias, stats);
  k3_out     <<<dim3(B_*256),  dim3(256),   0, stream>>>(features, W, idxw, stats, outF);
}